// Round 9
// baseline (366.796 us; speedup 1.0000x reference)
//
#include <hip/hip_runtime.h>
#include <hip/hip_bf16.h>
#include <math.h>

// QwenStyleSparseMoEBlock: T=4096, D=1024, F=2048, E=4, top-2.
// R8 (compile fix: removed fwd-referenced l15_dummy helper): overlap round.
//   GEMM1: 256x256xBK64 8-wave 8-phase (4 phases/K-tile), 128KiB dbuf LDS,
//          gate+up interleaved Wcat B operand, G4 swizzle (byte ^= (row&7)<<4)
//          on stage-source + read, per-K-tile vmcnt(0)+barrier at iteration TOP
//          (waits loads issued one full iteration earlier — counted in effect),
//          setprio(1) around MFMA clusters.
//   GEMM2: counted 2-phase (T3-minimum): dbuf, stage(next) BEFORE compute(cur),
//          single vmcnt(0)+s_barrier per iteration END. Pad-256 H addressing.
//   Routing fused with X->bf16; R4-verified Wcat/Wdt transpose prepass.

typedef float  f32x4 __attribute__((ext_vector_type(4)));
typedef short  s16x8 __attribute__((ext_vector_type(8)));

__device__ __forceinline__ unsigned short f2bf(float f) {
  union { float f; unsigned int u; } v; v.f = f;
  return (unsigned short)((v.u + 0x7fffu + ((v.u >> 16) & 1u)) >> 16);  // RNE
}

__device__ __forceinline__ void glds16(const void* g, void* l) {
  __builtin_amdgcn_global_load_lds(
      (const __attribute__((address_space(1))) void*)g,
      (__attribute__((address_space(3))) void*)l, 16, 0, 0);
}

// ---------------- routing + X conversion ----------------
__global__ void k_routing(const float* __restrict__ x, const float* __restrict__ wg,
                          float* __restrict__ cw, int* __restrict__ idx,
                          int* __restrict__ cnt, unsigned short* __restrict__ Xb) {
  const int lane = threadIdx.x & 63;
  const int tok  = blockIdx.x * 4 + (threadIdx.x >> 6);
  const float4* X4 = (const float4*)x + (size_t)tok * 256;
  const float4* W4 = (const float4*)wg;
  ushort4* O4 = (ushort4*)Xb + (size_t)tok * 256;
  float a0 = 0.f, a1 = 0.f, a2 = 0.f, a3 = 0.f;
#pragma unroll
  for (int j = 0; j < 4; ++j) {
    const int d4 = j * 64 + lane;
    const float4 v = X4[d4];
    ushort4 o;
    o.x = f2bf(v.x); o.y = f2bf(v.y); o.z = f2bf(v.z); o.w = f2bf(v.w);
    O4[d4] = o;
    float4 w;
    w = W4[0 * 256 + d4]; a0 += v.x * w.x + v.y * w.y + v.z * w.z + v.w * w.w;
    w = W4[1 * 256 + d4]; a1 += v.x * w.x + v.y * w.y + v.z * w.z + v.w * w.w;
    w = W4[2 * 256 + d4]; a2 += v.x * w.x + v.y * w.y + v.z * w.z + v.w * w.w;
    w = W4[3 * 256 + d4]; a3 += v.x * w.x + v.y * w.y + v.z * w.z + v.w * w.w;
  }
#pragma unroll
  for (int off = 32; off; off >>= 1) {
    a0 += __shfl_xor(a0, off);
    a1 += __shfl_xor(a1, off);
    a2 += __shfl_xor(a2, off);
    a3 += __shfl_xor(a3, off);
  }
  if (lane == 0) {
    float l[4] = {a0, a1, a2, a3};
    const float m = fmaxf(fmaxf(l[0], l[1]), fmaxf(l[2], l[3]));
    float p[4];
#pragma unroll
    for (int e = 0; e < 4; ++e) p[e] = expf(l[e] - m);
    int i1 = 0; float b1 = p[0];
#pragma unroll
    for (int e = 1; e < 4; ++e) if (p[e] > b1) { b1 = p[e]; i1 = e; }
    int i2 = -1; float b2 = -1.f;
#pragma unroll
    for (int e = 0; e < 4; ++e) if (e != i1 && p[e] > b2) { b2 = p[e]; i2 = e; }
    const float inv = 1.f / (b1 + b2);
    float o[4] = {0.f, 0.f, 0.f, 0.f};
    o[i1] = b1 * inv; o[i2] = b2 * inv;
    *(float4*)(cw + (size_t)tok * 4) = make_float4(o[0], o[1], o[2], o[3]);
    const int p1 = atomicAdd(&cnt[i1], 1); idx[i1 * 4096 + p1] = tok;
    const int p2 = atomicAdd(&cnt[i2], 1); idx[i2 * 4096 + p2] = tok;
  }
}

// off[0..3]=row base (pad-256); off[4..8]=prefix of ceil256 (GEMM1 tiles);
// off[9..13]=prefix of ceil128 (GEMM2 tiles)
__global__ void k_offsets(const int* __restrict__ cnt, int* __restrict__ off) {
  if (threadIdx.x == 0 && blockIdx.x == 0) {
    int o = 0, q = 0, p = 0;
#pragma unroll
    for (int e = 0; e < 4; ++e) {
      off[e] = o; off[4 + e] = q; off[9 + e] = p;
      o += (cnt[e] + 255) & ~255;
      q += (cnt[e] + 255) >> 8;
      p += (cnt[e] + 127) >> 7;
    }
    off[8] = q; off[13] = p;
  }
}

// ---------------- weights -> transposed bf16; gate/up interleaved into Wcat ----------------
// grid (32,16,12), block (64,4). Wcat row for f: gate -> (f>>4)*32+(f&15); up -> +16.
__global__ void k_tcvt_all(const float* __restrict__ wgp, const float* __restrict__ wup,
                           const float* __restrict__ wdp,
                           unsigned short* __restrict__ Wcat,
                           unsigned short* __restrict__ Wdt) {
  __shared__ float t[64][65];
  const int z = blockIdx.z;
  const int tx = threadIdx.x, ty = threadIdx.y;
  const float* in; unsigned short* outp; int R, C, c0, r0, cat = 0, addup = 0;
  if (z < 8) {
    R = 1024; C = 2048;
    const int e = z & 3;
    in   = (z < 4 ? wgp : wup) + (size_t)e * 1024 * 2048;
    outp = Wcat + (size_t)e * 4096 * 1024;
    c0 = blockIdx.x * 64; r0 = blockIdx.y * 64;
    cat = 1; addup = (z >= 4) ? 16 : 0;
  } else {
    R = 2048; C = 1024;
    const int e = z & 3;
    in   = wdp + (size_t)e * 2048 * 1024;
    outp = Wdt + (size_t)e * 2048 * 1024;
    c0 = blockIdx.y * 64; r0 = blockIdx.x * 64;
  }
#pragma unroll
  for (int i = 0; i < 16; ++i) {
    const int r = i * 4 + ty;
    t[r][tx] = in[(size_t)(r0 + r) * C + c0 + tx];
  }
  __syncthreads();
#pragma unroll
  for (int i = 0; i < 16; ++i) {
    const int cc = i * 4 + ty;
    const int f = c0 + cc;
    const int orow = cat ? (((f >> 4) << 5) + (f & 15) + addup) : f;
    outp[(size_t)orow * R + r0 + tx] = f2bf(t[tx][cc]);
  }
}

// ---------------- GEMM1: H = gelu(Xg@Wg)*(Xg@Wu), 256x256, 8-phase ----------------
// grid 576 = 16 bn x 36 mt, bn-major XCD chunks (chunk=72)
__global__ __launch_bounds__(512, 2)
void k_gemm1(const unsigned short* __restrict__ Xb,
             const unsigned short* __restrict__ Wcat,
             unsigned short* __restrict__ H,
             const int* __restrict__ idx, const int* __restrict__ cnt,
             const int* __restrict__ off) {
  const int w0 = (blockIdx.x & 7) * 72 + (blockIdx.x >> 3);
  const int bn = w0 / 36, mt = w0 % 36;
  const int* t1 = off + 4;
  if (mt >= t1[4]) return;
  const int e = (mt >= t1[1]) + (mt >= t1[2]) + (mt >= t1[3]);
  const int local = mt - t1[e];
  const int cn = cnt[e];
  const int lr0 = local * 256;
  const int hrow0 = off[e] + lr0;

  __shared__ __align__(16) unsigned short lds[2][2][256 * 64];  // 128 KiB

  const int tid = threadIdx.x;
  const int lane = tid & 63, wv = tid >> 6;
  const int wm = wv >> 2, wn = wv & 3;            // 2 x 4 waves
  const int l15 = lane & 15;
  // read-side swizzled k-offsets (bytes): kb = (ks*64 + (lane>>4)*16) ^ ((row&7)<<4),
  // row&7 == lane&7 for all fragment rows here.
  const int kb0 = ((lane >> 4) * 16) ^ ((lane & 7) << 4);
  const int kb1 = kb0 ^ 64;

  // staging: round j covers rows j*64 + wv*8 + (lane>>3); LDS dest linear
  // (wave-uniform base), source col pre-swizzled by (row&7).
  const int lrow = lane >> 3;
  const int scol = ((lane & 7) ^ lrow) * 8;   // source col (elements)
  const int wbase = wv * 8;

  int tk[4];
#pragma unroll
  for (int j = 0; j < 4; ++j)
    tk[j] = idx[e * 4096 + min(lr0 + j * 64 + wbase + lrow, cn - 1)];

  const unsigned short* Wb = Wcat + (size_t)e * 4096 * 1024 + (size_t)(bn * 256) * 1024;

  f32x4 acc[8][4] = {};

  // prologue: stage K-tile 0 -> dbuf 0 (waited at first loop-top)
#pragma unroll
  for (int j = 0; j < 4; ++j)
    glds16(Xb + (size_t)tk[j] * 1024 + scol, &lds[0][0][(j * 64 + wbase) * 64]);
#pragma unroll
  for (int j = 0; j < 4; ++j)
    glds16(Wb + (size_t)(j * 64 + wbase + lrow) * 1024 + scol, &lds[0][1][(j * 64 + wbase) * 64]);

  for (int kt = 0; kt < 16; ++kt) {
    const int cur = kt & 1;
    const unsigned short* Ab = lds[cur][0];
    const unsigned short* Bb = lds[cur][1];
    unsigned short* Ad = lds[cur ^ 1][0];
    unsigned short* Bd = lds[cur ^ 1][1];
    const int kn = (kt + 1) * 64;
    const bool pf = (kt < 15);

    // wait the 8 loads issued one full iteration ago (next tile's loads are
    // issued only after this point -> they stay in flight across it)
    asm volatile("s_waitcnt vmcnt(0)" ::: "memory");
    asm volatile("s_barrier" ::: "memory");

    s16x8 bfr[4][2];
#pragma unroll
    for (int p = 0; p < 4; ++p) {
      const s16x8 a0k0 = *(const s16x8*)((const char*)Ab + (wm * 128 + (2 * p) * 16 + l15) * 128 + kb0);
      const s16x8 a0k1 = *(const s16x8*)((const char*)Ab + (wm * 128 + (2 * p) * 16 + l15) * 128 + kb1);
      const s16x8 a1k0 = *(const s16x8*)((const char*)Ab + (wm * 128 + (2 * p + 1) * 16 + l15) * 128 + kb0);
      const s16x8 a1k1 = *(const s16x8*)((const char*)Ab + (wm * 128 + (2 * p + 1) * 16 + l15) * 128 + kb1);
      if (p == 0) {
#pragma unroll
        for (int ni = 0; ni < 4; ++ni) {
          bfr[ni][0] = *(const s16x8*)((const char*)Bb + (wn * 64 + ni * 16 + l15) * 128 + kb0);
          bfr[ni][1] = *(const s16x8*)((const char*)Bb + (wn * 64 + ni * 16 + l15) * 128 + kb1);
        }
      }
      if (pf) {
        if (p < 2) {
#pragma unroll
          for (int j = 2 * p; j < 2 * p + 2; ++j)
            glds16(Xb + (size_t)tk[j] * 1024 + kn + scol, &Ad[(j * 64 + wbase) * 64]);
        } else {
#pragma unroll
          for (int j = 2 * (p - 2); j < 2 * (p - 2) + 2; ++j)
            glds16(Wb + (size_t)(j * 64 + wbase + lrow) * 1024 + kn + scol, &Bd[(j * 64 + wbase) * 64]);
        }
      }
      asm volatile("s_barrier" ::: "memory");
      __builtin_amdgcn_s_setprio(1);
#pragma unroll
      for (int ni = 0; ni < 4; ++ni) {
        acc[2 * p][ni]     = __builtin_amdgcn_mfma_f32_16x16x32_bf16(a0k0, bfr[ni][0], acc[2 * p][ni], 0, 0, 0);
        acc[2 * p][ni]     = __builtin_amdgcn_mfma_f32_16x16x32_bf16(a0k1, bfr[ni][1], acc[2 * p][ni], 0, 0, 0);
        acc[2 * p + 1][ni] = __builtin_amdgcn_mfma_f32_16x16x32_bf16(a1k0, bfr[ni][0], acc[2 * p + 1][ni], 0, 0, 0);
        acc[2 * p + 1][ni] = __builtin_amdgcn_mfma_f32_16x16x32_bf16(a1k1, bfr[ni][1], acc[2 * p + 1][ni], 0, 0, 0);
      }
      __builtin_amdgcn_s_setprio(0);
      if (p < 3) asm volatile("s_barrier" ::: "memory");
    }
  }

  // epilogue: gelu(g)*u from interleaved (gate,up) N-frag pairs
  const int rbase = hrow0 + wm * 128;
#pragma unroll
  for (int mi = 0; mi < 8; ++mi)
#pragma unroll
    for (int q = 0; q < 2; ++q)
#pragma unroll
      for (int r = 0; r < 4; ++r) {
        const int row = rbase + mi * 16 + (lane >> 4) * 4 + r;
        const int col = bn * 128 + wn * 32 + q * 16 + l15;
        const float g = acc[mi][2 * q][r];
        const float u = acc[mi][2 * q + 1][r];
        const float h = 0.5f * g * (1.0f + erff(g * 0.70710678118654752f)) * u;
        H[(size_t)row * 2048 + col] = f2bf(h);
      }
}

// ---------------- GEMM2: out += cw * (H_e @ Wd_e), counted 2-phase ----------------
// grid 544 = 68 mt x 8 bn, mt-major XCD chunks (chunk=68)
__global__ __launch_bounds__(256, 2)
void k_gemm2(const unsigned short* __restrict__ H,
             const unsigned short* __restrict__ Wdt,
             const float* __restrict__ cw,
             const int* __restrict__ idx, const int* __restrict__ cnt,
             const int* __restrict__ off,
             float* __restrict__ out) {
  const int w = (blockIdx.x & 7) * 68 + (blockIdx.x >> 3);
  const int mt = w >> 3, bn = w & 7;
  const int* t2 = off + 9;
  if (mt >= t2[4]) return;
  const int e = (mt >= t2[1]) + (mt >= t2[2]) + (mt >= t2[3]);
  const int local = mt - t2[e];
  const int cn = cnt[e];
  const int lr0 = local * 128;
  const int hrow0 = off[e] + lr0;

  __shared__ __align__(16) unsigned short sA[2][128 * 64];
  __shared__ __align__(16) unsigned short sB[2][128 * 64];
  const int tid = threadIdx.x;
  const int lane = tid & 63, wid = tid >> 6;
  const int wm = wid >> 1, wn = wid & 1;
  const int lrow = lane >> 3;
  const int lc8 = (lane & 7) * 8;

  const unsigned short* Ha = H + (size_t)hrow0 * 2048;
  const unsigned short* Wd = Wdt + (size_t)e * 1024 * 2048 + (size_t)(bn * 128) * 2048;

  f32x4 acc[4][4] = {};

#define G2_STAGE(d, k0)                                                        \
  {                                                                            \
    _Pragma("unroll")                                                          \
    for (int i = 0; i < 4; ++i) {                                              \
      const int c = wid * 4 + i;                                               \
      const int row = c * 8 + lrow;                                            \
      glds16(Ha + (size_t)row * 2048 + (k0) + lc8, &sA[d][c * 512]);           \
      glds16(Wd + (size_t)row * 2048 + (k0) + lc8, &sB[d][c * 512]);           \
    }                                                                          \
  }

  G2_STAGE(0, 0)
  asm volatile("s_waitcnt vmcnt(0)" ::: "memory");
  asm volatile("s_barrier" ::: "memory");

  for (int kt = 0; kt < 32; ++kt) {
    const int cur = kt & 1;
    if (kt < 31) G2_STAGE(cur ^ 1, (kt + 1) * 64)
#pragma unroll
    for (int ks = 0; ks < 2; ++ks) {
      const int ko = ks * 32 + (lane >> 4) * 8;
      s16x8 a[4], b[4];
#pragma unroll
      for (int mi = 0; mi < 4; ++mi)
        a[mi] = *(const s16x8*)&sA[cur][(wm * 64 + mi * 16 + (lane & 15)) * 64 + ko];
#pragma unroll
      for (int ni = 0; ni < 4; ++ni)
        b[ni] = *(const s16x8*)&sB[cur][(wn * 64 + ni * 16 + (lane & 15)) * 64 + ko];
#pragma unroll
      for (int mi = 0; mi < 4; ++mi)
#pragma unroll
        for (int ni = 0; ni < 4; ++ni)
          acc[mi][ni] = __builtin_amdgcn_mfma_f32_16x16x32_bf16(a[mi], b[ni], acc[mi][ni], 0, 0, 0);
    }
    asm volatile("s_waitcnt vmcnt(0)" ::: "memory");
    asm volatile("s_barrier" ::: "memory");
  }
#undef G2_STAGE

#pragma unroll
  for (int mi = 0; mi < 4; ++mi)
#pragma unroll
    for (int r = 0; r < 4; ++r) {
      const int lr = lr0 + wm * 64 + mi * 16 + (lane >> 4) * 4 + r;
      if (lr < cn) {
        const int tok = idx[e * 4096 + lr];
        const float wgt = cw[(size_t)tok * 4 + e];
        float* orow = out + (size_t)tok * 1024 + bn * 128 + wn * 64 + (lane & 15);
#pragma unroll
        for (int ni = 0; ni < 4; ++ni)
          atomicAdd(orow + ni * 16, acc[mi][ni][r] * wgt);
      }
    }
}

extern "C" void kernel_launch(void* const* d_in, const int* in_sizes, int n_in,
                              void* d_out, int out_size, void* d_ws, size_t ws_size,
                              hipStream_t stream) {
  const float* x     = (const float*)d_in[0];
  const float* wgate = (const float*)d_in[1];
  const float* wgp   = (const float*)d_in[2];
  const float* wup   = (const float*)d_in[3];
  const float* wdp   = (const float*)d_in[4];
  float* out = (float*)d_out;

  char* ws = (char*)d_ws;
  float* cw            = (float*)ws;                       // 64 KB
  int*   idx           = (int*)(ws + 65536);               // 64 KB
  int*   cnt           = (int*)(ws + 131072);              // 16 B
  int*   off           = (int*)(ws + 131136);              // 56 B
  unsigned short* Xb   = (unsigned short*)(ws + 131584);   // 8 MB
  unsigned short* Wcat = Xb   + (size_t)4096 * 1024;       // 32 MB
  unsigned short* Wdt  = Wcat + (size_t)4 * 4096 * 1024;   // 16 MB
  unsigned short* H    = Wdt  + (size_t)4 * 1024 * 2048;   // 9216 x 2048 bf16
  // total ~92.1 MiB (same layout R4 ran with)

  hipMemsetAsync(cnt, 0, 16, stream);
  hipMemsetAsync(out, 0, (size_t)4096 * 1024 * 4, stream);
  k_routing<<<1024, 256, 0, stream>>>(x, wgate, cw, idx, cnt, Xb);
  k_offsets<<<1, 64, 0, stream>>>(cnt, off);
  k_tcvt_all<<<dim3(32, 16, 12), dim3(64, 4), 0, stream>>>(wgp, wup, wdp, Wcat, Wdt);

  k_gemm1<<<576, 512, 0, stream>>>(Xb, Wcat, H, idx, cnt, off);
  k_gemm2<<<544, 256, 0, stream>>>(H, Wdt, cw, idx, cnt, off, out);
}

// Round 10
// 345.986 us; speedup vs baseline: 1.0601x; 1.0601x over previous
//
#include <hip/hip_runtime.h>
#include <hip/hip_bf16.h>
#include <math.h>

// QwenStyleSparseMoEBlock: T=4096, D=1024, F=2048, E=4, top-2.
// R10: GEMM1 = R7-exact (123.4us known-good). GEMM2 = TLP round:
//   split-K x2 (grid 1072, 4 atomic contribs/elem), launch_bounds(256,4)
//   (VGPR ~106 = 64 acc + ~42 work < 128 budget), single-buffer 32KB LDS,
//   G4 swizzle (byte ^= (row&7)<<4; source-col pre-swizzle + read XOR —
//   correctness of this involution verified by R9's passing gemm1).
// R9 lesson: T3-min dbuf on 2-phase = neutral/negative (m99/m233); GEMM2 is
// latency/TLP-bound (MfmaUtil 10%, VALUBusy 5.6%) -> raise resident waves.

typedef float  f32x4 __attribute__((ext_vector_type(4)));
typedef short  s16x8 __attribute__((ext_vector_type(8)));

__device__ __forceinline__ unsigned short f2bf(float f) {
  union { float f; unsigned int u; } v; v.f = f;
  return (unsigned short)((v.u + 0x7fffu + ((v.u >> 16) & 1u)) >> 16);  // RNE
}

__device__ __forceinline__ void glds16(const void* g, void* l) {
  __builtin_amdgcn_global_load_lds(
      (const __attribute__((address_space(1))) void*)g,
      (__attribute__((address_space(3))) void*)l, 16, 0, 0);
}

// ---------------- routing + X conversion ----------------
__global__ void k_routing(const float* __restrict__ x, const float* __restrict__ wg,
                          float* __restrict__ cw, int* __restrict__ idx,
                          int* __restrict__ cnt, unsigned short* __restrict__ Xb) {
  const int lane = threadIdx.x & 63;
  const int tok  = blockIdx.x * 4 + (threadIdx.x >> 6);
  const float4* X4 = (const float4*)x + (size_t)tok * 256;
  const float4* W4 = (const float4*)wg;
  ushort4* O4 = (ushort4*)Xb + (size_t)tok * 256;
  float a0 = 0.f, a1 = 0.f, a2 = 0.f, a3 = 0.f;
#pragma unroll
  for (int j = 0; j < 4; ++j) {
    const int d4 = j * 64 + lane;
    const float4 v = X4[d4];
    ushort4 o;
    o.x = f2bf(v.x); o.y = f2bf(v.y); o.z = f2bf(v.z); o.w = f2bf(v.w);
    O4[d4] = o;
    float4 w;
    w = W4[0 * 256 + d4]; a0 += v.x * w.x + v.y * w.y + v.z * w.z + v.w * w.w;
    w = W4[1 * 256 + d4]; a1 += v.x * w.x + v.y * w.y + v.z * w.z + v.w * w.w;
    w = W4[2 * 256 + d4]; a2 += v.x * w.x + v.y * w.y + v.z * w.z + v.w * w.w;
    w = W4[3 * 256 + d4]; a3 += v.x * w.x + v.y * w.y + v.z * w.z + v.w * w.w;
  }
#pragma unroll
  for (int off = 32; off; off >>= 1) {
    a0 += __shfl_xor(a0, off);
    a1 += __shfl_xor(a1, off);
    a2 += __shfl_xor(a2, off);
    a3 += __shfl_xor(a3, off);
  }
  if (lane == 0) {
    float l[4] = {a0, a1, a2, a3};
    const float m = fmaxf(fmaxf(l[0], l[1]), fmaxf(l[2], l[3]));
    float p[4];
#pragma unroll
    for (int e = 0; e < 4; ++e) p[e] = expf(l[e] - m);
    int i1 = 0; float b1 = p[0];
#pragma unroll
    for (int e = 1; e < 4; ++e) if (p[e] > b1) { b1 = p[e]; i1 = e; }
    int i2 = -1; float b2 = -1.f;
#pragma unroll
    for (int e = 0; e < 4; ++e) if (e != i1 && p[e] > b2) { b2 = p[e]; i2 = e; }
    const float inv = 1.f / (b1 + b2);
    float o[4] = {0.f, 0.f, 0.f, 0.f};
    o[i1] = b1 * inv; o[i2] = b2 * inv;
    *(float4*)(cw + (size_t)tok * 4) = make_float4(o[0], o[1], o[2], o[3]);
    const int p1 = atomicAdd(&cnt[i1], 1); idx[i1 * 4096 + p1] = tok;
    const int p2 = atomicAdd(&cnt[i2], 1); idx[i2 * 4096 + p2] = tok;
  }
}

// off[e] = prefix sum of pad128(cnt) (rows)
__global__ void k_offsets(const int* __restrict__ cnt, int* __restrict__ off) {
  if (threadIdx.x == 0 && blockIdx.x == 0) {
    int o = 0;
#pragma unroll
    for (int e = 0; e < 4; ++e) { off[e] = o; o += (cnt[e] + 127) & ~127; }
  }
}

// ---------------- all W [R][C] fp32 -> Wt [C][R] bf16, one launch ----------------
__global__ void k_tcvt_all(const float* __restrict__ wgp, const float* __restrict__ wup,
                           const float* __restrict__ wdp,
                           unsigned short* __restrict__ Wgt, unsigned short* __restrict__ Wut,
                           unsigned short* __restrict__ Wdt) {
  __shared__ float t[32][33];
  const int z = blockIdx.z;
  const float* in; unsigned short* out; int R, C, c0, r0;
  if (z < 8) {
    R = 1024; C = 2048;
    const int e = z & 3;
    in  = (z < 4 ? wgp : wup) + (size_t)e * 1024 * 2048;
    out = (z < 4 ? Wgt : Wut) + (size_t)e * 1024 * 2048;
    c0 = blockIdx.x * 32; r0 = blockIdx.y * 32;
  } else {
    R = 2048; C = 1024;
    const int e = z & 3;
    in  = wdp + (size_t)e * 2048 * 1024;
    out = Wdt + (size_t)e * 2048 * 1024;
    c0 = blockIdx.y * 32; r0 = blockIdx.x * 32;
  }
  const int tx = threadIdx.x, ty = threadIdx.y;   // 32 x 8
#pragma unroll
  for (int i = 0; i < 4; ++i)
    t[ty + 8 * i][tx] = in[(size_t)(r0 + ty + 8 * i) * C + c0 + tx];
  __syncthreads();
#pragma unroll
  for (int i = 0; i < 4; ++i)
    out[(size_t)(c0 + ty + 8 * i) * R + r0 + tx] = f2bf(t[tx][ty + 8 * i]);
}

// ---------------- GEMM1: H[mt*128+r][f] = gelu(x_g @ Wg) * (x_g @ Wu) ----------------
// grid: 1072 = 16 bn x 67 mt, bn-major XCD chunks (chunk = 134)   [R7-exact]
__global__ __launch_bounds__(256, 2)
void k_gemm1(const unsigned short* __restrict__ Xb,
             const unsigned short* __restrict__ Wgt,
             const unsigned short* __restrict__ Wut,
             unsigned short* __restrict__ H,
             const int* __restrict__ idx, const int* __restrict__ cnt,
             const int* __restrict__ off) {
  const int w  = (blockIdx.x & 7) * 134 + (blockIdx.x >> 3);  // bijective, 1072=8*134
  const int bn = w / 67, mt = w % 67;
  const int o1 = off[1] >> 7, o2 = off[2] >> 7, o3 = off[3] >> 7;
  if (mt >= o3 + ((cnt[3] + 127) >> 7)) return;
  const int e  = (mt >= o1) + (mt >= o2) + (mt >= o3);
  const int ob = (e == 0) ? 0 : (e == 1 ? o1 : (e == 2 ? o2 : o3));
  const int cn = cnt[e];
  const int lr0 = (mt - ob) * 128;

  __shared__ __align__(16) unsigned short sA[128 * 64];
  __shared__ __align__(16) unsigned short sG[128 * 64];
  __shared__ __align__(16) unsigned short sU[128 * 64];
  const int tid = threadIdx.x;
  const int lane = tid & 63, wid = tid >> 6;
  const int wm = wid >> 1, wn = wid & 1;

  f32x4 accg[4][4] = {};
  f32x4 accu[4][4] = {};

  const int srow = lane >> 3;
  const int scol = (lane & 7) * 8;
  int tk[4];
#pragma unroll
  for (int i = 0; i < 4; ++i) {
    const int row = (wid * 4 + i) * 8 + srow;
    tk[i] = idx[e * 4096 + min(lr0 + row, cn - 1)];
  }
  const unsigned short* Wg = Wgt + (size_t)e * 2048 * 1024 + (size_t)(bn * 128) * 1024;
  const unsigned short* Wu = Wut + (size_t)e * 2048 * 1024 + (size_t)(bn * 128) * 1024;

  for (int kt = 0; kt < 16; ++kt) {
    const int k0 = kt * 64;
#pragma unroll
    for (int i = 0; i < 4; ++i) {
      const int c = wid * 4 + i;
      const int row = c * 8 + srow;
      glds16(Xb + (size_t)tk[i] * 1024 + k0 + scol, &sA[c * 512]);
      glds16(Wg + (size_t)row * 1024 + k0 + scol, &sG[c * 512]);
      glds16(Wu + (size_t)row * 1024 + k0 + scol, &sU[c * 512]);
    }
    __syncthreads();
#pragma unroll
    for (int ks = 0; ks < 2; ++ks) {
      const int ko = ks * 32 + (lane >> 4) * 8;
      s16x8 a[4], bg[4], bu[4];
#pragma unroll
      for (int mi = 0; mi < 4; ++mi)
        a[mi] = *(const s16x8*)&sA[(wm * 64 + mi * 16 + (lane & 15)) * 64 + ko];
#pragma unroll
      for (int ni = 0; ni < 4; ++ni) {
        bg[ni] = *(const s16x8*)&sG[(wn * 64 + ni * 16 + (lane & 15)) * 64 + ko];
        bu[ni] = *(const s16x8*)&sU[(wn * 64 + ni * 16 + (lane & 15)) * 64 + ko];
      }
#pragma unroll
      for (int mi = 0; mi < 4; ++mi)
#pragma unroll
        for (int ni = 0; ni < 4; ++ni) {
          accg[mi][ni] = __builtin_amdgcn_mfma_f32_16x16x32_bf16(a[mi], bg[ni], accg[mi][ni], 0, 0, 0);
          accu[mi][ni] = __builtin_amdgcn_mfma_f32_16x16x32_bf16(a[mi], bu[ni], accu[mi][ni], 0, 0, 0);
        }
    }
    __syncthreads();
  }
  const int r0 = mt * 128 + wm * 64;
  const int c0 = bn * 128 + wn * 64;
#pragma unroll
  for (int mi = 0; mi < 4; ++mi)
#pragma unroll
    for (int ni = 0; ni < 4; ++ni)
#pragma unroll
      for (int r = 0; r < 4; ++r) {
        const int row = r0 + mi * 16 + (lane >> 4) * 4 + r;
        const int col = c0 + ni * 16 + (lane & 15);
        const float g = accg[mi][ni][r];
        const float u = accu[mi][ni][r];
        const float h = 0.5f * g * (1.0f + erff(g * 0.70710678118654752f)) * u;
        H[(size_t)row * 2048 + col] = f2bf(h);
      }
}

// ---------------- GEMM2: out[tok][d] += cw[tok][e] * (H_e @ Wd_e) ----------------
// split-K x2: grid 1072 = 2 kh x 67 mt x 8 bn; XCD chunk 134 (XCDs 0-3 kh=0,
// 4-7 kh=1; mt-major within each half). 4 blocks/CU. G4-swizzled LDS.
__global__ __launch_bounds__(256, 4)
void k_gemm2(const unsigned short* __restrict__ H,
             const unsigned short* __restrict__ Wdt,
             const float* __restrict__ cw,
             const int* __restrict__ idx, const int* __restrict__ cnt,
             const int* __restrict__ off,
             float* __restrict__ out) {
  const int w  = (blockIdx.x & 7) * 134 + (blockIdx.x >> 3);  // bijective, 1072=8*134
  const int kh = (w >= 536) ? 1 : 0;
  const int w2 = w - kh * 536;
  const int mt = w2 >> 3, bn = w2 & 7;
  const int o1 = off[1] >> 7, o2 = off[2] >> 7, o3 = off[3] >> 7;
  if (mt >= o3 + ((cnt[3] + 127) >> 7)) return;
  const int e  = (mt >= o1) + (mt >= o2) + (mt >= o3);
  const int ob = (e == 0) ? 0 : (e == 1 ? o1 : (e == 2 ? o2 : o3));
  const int cn = cnt[e];
  const int lr0 = (mt - ob) * 128;

  __shared__ __align__(16) unsigned short sA[128 * 64];
  __shared__ __align__(16) unsigned short sB[128 * 64];
  const int lane = threadIdx.x & 63, wid = threadIdx.x >> 6;
  const int wm = wid >> 1, wn = wid & 1;
  const int lrow = lane >> 3;                       // row&7 of the staged row
  const int scol = ((lane & 7) ^ lrow) * 8;         // G4 pre-swizzled source col
  const int kb0  = ((lane >> 4) * 16) ^ ((lane & 7) << 4);  // read-side swizzle
  const int kb1  = kb0 ^ 64;
  const int l15  = lane & 15;

  f32x4 acc[4][4] = {};
  const unsigned short* Ha = H + (size_t)(mt * 128) * 2048 + kh * 1024;
  const unsigned short* Wd = Wdt + (size_t)e * 1024 * 2048 + (size_t)(bn * 128) * 2048 + kh * 1024;

  for (int kt = 0; kt < 16; ++kt) {
    const int k0 = kt * 64;
#pragma unroll
    for (int i = 0; i < 4; ++i) {
      const int c = wid * 4 + i;
      const int row = c * 8 + lrow;
      glds16(Ha + (size_t)row * 2048 + k0 + scol, &sA[c * 512]);
      glds16(Wd + (size_t)row * 2048 + k0 + scol, &sB[c * 512]);
    }
    __syncthreads();
#pragma unroll
    for (int ks = 0; ks < 2; ++ks) {
      const int kb = ks ? kb1 : kb0;
      s16x8 a[4], b[4];
#pragma unroll
      for (int mi = 0; mi < 4; ++mi)
        a[mi] = *(const s16x8*)((const char*)sA + (wm * 64 + mi * 16 + l15) * 128 + kb);
#pragma unroll
      for (int ni = 0; ni < 4; ++ni)
        b[ni] = *(const s16x8*)((const char*)sB + (wn * 64 + ni * 16 + l15) * 128 + kb);
#pragma unroll
      for (int mi = 0; mi < 4; ++mi)
#pragma unroll
        for (int ni = 0; ni < 4; ++ni)
          acc[mi][ni] = __builtin_amdgcn_mfma_f32_16x16x32_bf16(a[mi], b[ni], acc[mi][ni], 0, 0, 0);
    }
    __syncthreads();
  }
#pragma unroll
  for (int mi = 0; mi < 4; ++mi)
#pragma unroll
    for (int r = 0; r < 4; ++r) {
      const int lr = lr0 + wm * 64 + mi * 16 + (lane >> 4) * 4 + r;
      if (lr < cn) {
        const int tok = idx[e * 4096 + lr];
        const float wgt = cw[(size_t)tok * 4 + e];
        float* orow = out + (size_t)tok * 1024 + bn * 128 + wn * 64 + l15;
#pragma unroll
        for (int ni = 0; ni < 4; ++ni)
          atomicAdd(orow + ni * 16, acc[mi][ni][r] * wgt);
      }
    }
}

extern "C" void kernel_launch(void* const* d_in, const int* in_sizes, int n_in,
                              void* d_out, int out_size, void* d_ws, size_t ws_size,
                              hipStream_t stream) {
  const float* x     = (const float*)d_in[0];
  const float* wgate = (const float*)d_in[1];
  const float* wgp   = (const float*)d_in[2];
  const float* wup   = (const float*)d_in[3];
  const float* wdp   = (const float*)d_in[4];
  float* out = (float*)d_out;

  char* ws = (char*)d_ws;
  float* cw           = (float*)ws;                        // 64 KB
  int*   idx          = (int*)(ws + 65536);                // 64 KB
  int*   cnt          = (int*)(ws + 131072);               // 16 B
  int*   off          = (int*)(ws + 131328);               // 16 B
  unsigned short* Xb  = (unsigned short*)(ws + 131584);    // 8 MB
  unsigned short* Wgt = Xb  + (size_t)4096 * 1024;         // 16 MB
  unsigned short* Wut = Wgt + (size_t)4 * 2048 * 1024;     // 16 MB
  unsigned short* Wdt = Wut + (size_t)4 * 2048 * 1024;     // 16 MB
  unsigned short* H   = Wdt + (size_t)4 * 1024 * 2048;     // 8704 x 2048 bf16

  hipMemsetAsync(cnt, 0, 16, stream);
  hipMemsetAsync(out, 0, (size_t)4096 * 1024 * 4, stream);
  k_routing<<<1024, 256, 0, stream>>>(x, wgate, cw, idx, cnt, Xb);
  k_offsets<<<1, 64, 0, stream>>>(cnt, off);
  k_tcvt_all<<<dim3(64, 32, 12), dim3(32, 8), 0, stream>>>(wgp, wup, wdp, Wgt, Wut, Wdt);

  k_gemm1<<<1072, 256, 0, stream>>>(Xb, Wgt, Wut, H, idx, cnt, off);
  k_gemm2<<<1072, 256, 0, stream>>>(H, Wdt, cw, idx, cnt, off, out);
}

// Round 11
// 314.025 us; speedup vs baseline: 1.1680x; 1.1018x over previous
//
#include <hip/hip_runtime.h>
#include <hip/hip_bf16.h>
#include <math.h>

// QwenStyleSparseMoEBlock: T=4096, D=1024, F=2048, E=4, top-2.
// R11: GEMM1 = 256x256xBK64 8-wave T3-minimum counted schedule:
//   per K-tile: {vmcnt(0); s_barrier; STAGE(next tile, 8 glds16); read B frags;
//   4 x [read A pair; setprio(1); 16 MFMA; setprio(0)]}. No intra-iter barriers
//   (reads hit buf cur, stage writes buf cur^1). The vmcnt(0) waits loads issued
//   one full 64-MFMA iteration earlier -> true overlap (m218 counted semantics).
//   G4 swizzle (src col ^ row&7, read byte ^ (row&7)<<4) — R9/R10-verified.
//   Gate/up interleaved Wcat B operand; R9-verified epilogue math.
// GEMM2 = R7 internals exactly (single-buffer 2-phase, 2 atomic contribs/elem).
// R10 lesson: split-K doubled atomics -> +22us net; reverted.

typedef float  f32x4 __attribute__((ext_vector_type(4)));
typedef short  s16x8 __attribute__((ext_vector_type(8)));

__device__ __forceinline__ unsigned short f2bf(float f) {
  union { float f; unsigned int u; } v; v.f = f;
  return (unsigned short)((v.u + 0x7fffu + ((v.u >> 16) & 1u)) >> 16);  // RNE
}

__device__ __forceinline__ void glds16(const void* g, void* l) {
  __builtin_amdgcn_global_load_lds(
      (const __attribute__((address_space(1))) void*)g,
      (__attribute__((address_space(3))) void*)l, 16, 0, 0);
}

// ---------------- routing + X conversion ----------------
__global__ void k_routing(const float* __restrict__ x, const float* __restrict__ wg,
                          float* __restrict__ cw, int* __restrict__ idx,
                          int* __restrict__ cnt, unsigned short* __restrict__ Xb) {
  const int lane = threadIdx.x & 63;
  const int tok  = blockIdx.x * 4 + (threadIdx.x >> 6);
  const float4* X4 = (const float4*)x + (size_t)tok * 256;
  const float4* W4 = (const float4*)wg;
  ushort4* O4 = (ushort4*)Xb + (size_t)tok * 256;
  float a0 = 0.f, a1 = 0.f, a2 = 0.f, a3 = 0.f;
#pragma unroll
  for (int j = 0; j < 4; ++j) {
    const int d4 = j * 64 + lane;
    const float4 v = X4[d4];
    ushort4 o;
    o.x = f2bf(v.x); o.y = f2bf(v.y); o.z = f2bf(v.z); o.w = f2bf(v.w);
    O4[d4] = o;
    float4 w;
    w = W4[0 * 256 + d4]; a0 += v.x * w.x + v.y * w.y + v.z * w.z + v.w * w.w;
    w = W4[1 * 256 + d4]; a1 += v.x * w.x + v.y * w.y + v.z * w.z + v.w * w.w;
    w = W4[2 * 256 + d4]; a2 += v.x * w.x + v.y * w.y + v.z * w.z + v.w * w.w;
    w = W4[3 * 256 + d4]; a3 += v.x * w.x + v.y * w.y + v.z * w.z + v.w * w.w;
  }
#pragma unroll
  for (int off = 32; off; off >>= 1) {
    a0 += __shfl_xor(a0, off);
    a1 += __shfl_xor(a1, off);
    a2 += __shfl_xor(a2, off);
    a3 += __shfl_xor(a3, off);
  }
  if (lane == 0) {
    float l[4] = {a0, a1, a2, a3};
    const float m = fmaxf(fmaxf(l[0], l[1]), fmaxf(l[2], l[3]));
    float p[4];
#pragma unroll
    for (int e = 0; e < 4; ++e) p[e] = expf(l[e] - m);
    int i1 = 0; float b1 = p[0];
#pragma unroll
    for (int e = 1; e < 4; ++e) if (p[e] > b1) { b1 = p[e]; i1 = e; }
    int i2 = -1; float b2 = -1.f;
#pragma unroll
    for (int e = 0; e < 4; ++e) if (e != i1 && p[e] > b2) { b2 = p[e]; i2 = e; }
    const float inv = 1.f / (b1 + b2);
    float o[4] = {0.f, 0.f, 0.f, 0.f};
    o[i1] = b1 * inv; o[i2] = b2 * inv;
    *(float4*)(cw + (size_t)tok * 4) = make_float4(o[0], o[1], o[2], o[3]);
    const int p1 = atomicAdd(&cnt[i1], 1); idx[i1 * 4096 + p1] = tok;
    const int p2 = atomicAdd(&cnt[i2], 1); idx[i2 * 4096 + p2] = tok;
  }
}

// off[0..3]=row base (pad-256); off[4..8]=prefix of ceil256 (GEMM1 tiles);
// off[9..13]=prefix of ceil128 (GEMM2 tiles)
__global__ void k_offsets(const int* __restrict__ cnt, int* __restrict__ off) {
  if (threadIdx.x == 0 && blockIdx.x == 0) {
    int o = 0, q = 0, p = 0;
#pragma unroll
    for (int e = 0; e < 4; ++e) {
      off[e] = o; off[4 + e] = q; off[9 + e] = p;
      o += (cnt[e] + 255) & ~255;
      q += (cnt[e] + 255) >> 8;
      p += (cnt[e] + 127) >> 7;
    }
    off[8] = q; off[13] = p;
  }
}

// ---------------- weights -> transposed bf16; gate/up interleaved into Wcat ----------------
// grid (32,16,12), block (64,4). Wcat row for f: gate -> (f>>4)*32+(f&15); up -> +16.
__global__ void k_tcvt_all(const float* __restrict__ wgp, const float* __restrict__ wup,
                           const float* __restrict__ wdp,
                           unsigned short* __restrict__ Wcat,
                           unsigned short* __restrict__ Wdt) {
  __shared__ float t[64][65];
  const int z = blockIdx.z;
  const int tx = threadIdx.x, ty = threadIdx.y;
  const float* in; unsigned short* outp; int R, C, c0, r0, cat = 0, addup = 0;
  if (z < 8) {
    R = 1024; C = 2048;
    const int e = z & 3;
    in   = (z < 4 ? wgp : wup) + (size_t)e * 1024 * 2048;
    outp = Wcat + (size_t)e * 4096 * 1024;
    c0 = blockIdx.x * 64; r0 = blockIdx.y * 64;
    cat = 1; addup = (z >= 4) ? 16 : 0;
  } else {
    R = 2048; C = 1024;
    const int e = z & 3;
    in   = wdp + (size_t)e * 2048 * 1024;
    outp = Wdt + (size_t)e * 2048 * 1024;
    c0 = blockIdx.y * 64; r0 = blockIdx.x * 64;
  }
#pragma unroll
  for (int i = 0; i < 16; ++i) {
    const int r = i * 4 + ty;
    t[r][tx] = in[(size_t)(r0 + r) * C + c0 + tx];
  }
  __syncthreads();
#pragma unroll
  for (int i = 0; i < 16; ++i) {
    const int cc = i * 4 + ty;
    const int f = c0 + cc;
    const int orow = cat ? (((f >> 4) << 5) + (f & 15) + addup) : f;
    outp[(size_t)orow * R + r0 + tx] = f2bf(t[tx][cc]);
  }
}

// ---------------- GEMM1: H = gelu(Xg@Wg)*(Xg@Wu), 256x256, T3-min counted ----------------
// grid 576 = 16 bn x 36 mt, bn-major XCD chunks (chunk=72)
__global__ __launch_bounds__(512, 2)
void k_gemm1(const unsigned short* __restrict__ Xb,
             const unsigned short* __restrict__ Wcat,
             unsigned short* __restrict__ H,
             const int* __restrict__ idx, const int* __restrict__ cnt,
             const int* __restrict__ off) {
  const int w0 = (blockIdx.x & 7) * 72 + (blockIdx.x >> 3);
  const int bn = w0 / 36, mt = w0 % 36;
  const int* t1 = off + 4;
  if (mt >= t1[4]) return;
  const int e = (mt >= t1[1]) + (mt >= t1[2]) + (mt >= t1[3]);
  const int local = mt - t1[e];
  const int cn = cnt[e];
  const int lr0 = local * 256;
  const int hrow0 = off[e] + lr0;

  __shared__ __align__(16) unsigned short lds[2][2][256 * 64];  // 128 KiB

  const int tid = threadIdx.x;
  const int lane = tid & 63, wv = tid >> 6;
  const int wm = wv >> 2, wn = wv & 3;            // 2 x 4 waves
  const int l15 = lane & 15;
  const int kb0 = ((lane >> 4) * 16) ^ ((lane & 7) << 4);  // read swizzle (row&7==lane&7)
  const int kb1 = kb0 ^ 64;
  const int lrow = lane >> 3;
  const int scol = ((lane & 7) ^ lrow) * 8;       // source pre-swizzle (row&7==lrow)
  const int wbase = wv * 8;

  int tk[4];
#pragma unroll
  for (int j = 0; j < 4; ++j)
    tk[j] = idx[e * 4096 + min(lr0 + j * 64 + wbase + lrow, cn - 1)];

  const unsigned short* Wb = Wcat + (size_t)e * 4096 * 1024 + (size_t)(bn * 256) * 1024;

  f32x4 acc[8][4] = {};

  // prologue: stage K-tile 0 -> buf 0
#pragma unroll
  for (int j = 0; j < 4; ++j)
    glds16(Xb + (size_t)tk[j] * 1024 + scol, &lds[0][0][(j * 64 + wbase) * 64]);
#pragma unroll
  for (int j = 0; j < 4; ++j)
    glds16(Wb + (size_t)(j * 64 + wbase + lrow) * 1024 + scol, &lds[0][1][(j * 64 + wbase) * 64]);

  for (int kt = 0; kt < 16; ++kt) {
    const int cur = kt & 1;
    // tile kt's loads were issued one full iteration ago (64 MFMA elapsed)
    asm volatile("s_waitcnt vmcnt(0)" ::: "memory");
    asm volatile("s_barrier" ::: "memory");
    if (kt < 15) {  // stage tile kt+1 into the buffer freed at the barrier
      const int ko = (kt + 1) * 64;
#pragma unroll
      for (int j = 0; j < 4; ++j)
        glds16(Xb + (size_t)tk[j] * 1024 + ko + scol, &lds[cur ^ 1][0][(j * 64 + wbase) * 64]);
#pragma unroll
      for (int j = 0; j < 4; ++j)
        glds16(Wb + (size_t)(j * 64 + wbase + lrow) * 1024 + ko + scol, &lds[cur ^ 1][1][(j * 64 + wbase) * 64]);
    }
    const char* Ab = (const char*)lds[cur][0];
    const char* Bb = (const char*)lds[cur][1];
    s16x8 bfr[4][2];
#pragma unroll
    for (int ni = 0; ni < 4; ++ni) {
      const int row = wn * 64 + ni * 16 + l15;
      bfr[ni][0] = *(const s16x8*)(Bb + row * 128 + kb0);
      bfr[ni][1] = *(const s16x8*)(Bb + row * 128 + kb1);
    }
#pragma unroll
    for (int p = 0; p < 4; ++p) {
      const int r0a = wm * 128 + (2 * p) * 16 + l15;
      const int r1a = wm * 128 + (2 * p + 1) * 16 + l15;
      const s16x8 a0k0 = *(const s16x8*)(Ab + r0a * 128 + kb0);
      const s16x8 a0k1 = *(const s16x8*)(Ab + r0a * 128 + kb1);
      const s16x8 a1k0 = *(const s16x8*)(Ab + r1a * 128 + kb0);
      const s16x8 a1k1 = *(const s16x8*)(Ab + r1a * 128 + kb1);
      __builtin_amdgcn_s_setprio(1);
#pragma unroll
      for (int ni = 0; ni < 4; ++ni) {
        acc[2 * p][ni]     = __builtin_amdgcn_mfma_f32_16x16x32_bf16(a0k0, bfr[ni][0], acc[2 * p][ni], 0, 0, 0);
        acc[2 * p][ni]     = __builtin_amdgcn_mfma_f32_16x16x32_bf16(a0k1, bfr[ni][1], acc[2 * p][ni], 0, 0, 0);
        acc[2 * p + 1][ni] = __builtin_amdgcn_mfma_f32_16x16x32_bf16(a1k0, bfr[ni][0], acc[2 * p + 1][ni], 0, 0, 0);
        acc[2 * p + 1][ni] = __builtin_amdgcn_mfma_f32_16x16x32_bf16(a1k1, bfr[ni][1], acc[2 * p + 1][ni], 0, 0, 0);
      }
      __builtin_amdgcn_s_setprio(0);
    }
  }

  // epilogue: gelu(g)*u from interleaved (gate,up) N-frag pairs  [R9-verified]
  const int rbase = hrow0 + wm * 128;
#pragma unroll
  for (int mi = 0; mi < 8; ++mi)
#pragma unroll
    for (int q = 0; q < 2; ++q)
#pragma unroll
      for (int r = 0; r < 4; ++r) {
        const int row = rbase + mi * 16 + (lane >> 4) * 4 + r;
        const int col = bn * 128 + wn * 32 + q * 16 + l15;
        const float g = acc[mi][2 * q][r];
        const float u = acc[mi][2 * q + 1][r];
        const float h = 0.5f * g * (1.0f + erff(g * 0.70710678118654752f)) * u;
        H[(size_t)row * 2048 + col] = f2bf(h);
      }
}

// ---------------- GEMM2: out += cw * (H_e @ Wd_e), R7 internals ----------------
// grid 544 = 68 mt x 8 bn, mt-major XCD chunks (chunk=68); pad-256 H base decode
__global__ __launch_bounds__(256, 2)
void k_gemm2(const unsigned short* __restrict__ H,
             const unsigned short* __restrict__ Wdt,
             const float* __restrict__ cw,
             const int* __restrict__ idx, const int* __restrict__ cnt,
             const int* __restrict__ off,
             float* __restrict__ out) {
  const int w = (blockIdx.x & 7) * 68 + (blockIdx.x >> 3);
  const int mt = w >> 3, bn = w & 7;
  const int* t2 = off + 9;
  if (mt >= t2[4]) return;
  const int e = (mt >= t2[1]) + (mt >= t2[2]) + (mt >= t2[3]);
  const int local = mt - t2[e];
  const int cn = cnt[e];
  const int lr0 = local * 128;
  const int hrow0 = off[e] + lr0;

  __shared__ __align__(16) unsigned short sA[128 * 64];
  __shared__ __align__(16) unsigned short sB[128 * 64];
  const int tid = threadIdx.x;
  const int lane = tid & 63, wid = tid >> 6;
  const int wm = wid >> 1, wn = wid & 1;
  const int srow = lane >> 3;
  const int scol = (lane & 7) * 8;

  const unsigned short* Ha = H + (size_t)hrow0 * 2048;
  const unsigned short* Wd = Wdt + (size_t)e * 1024 * 2048 + (size_t)(bn * 128) * 2048;

  f32x4 acc[4][4] = {};

  for (int kt = 0; kt < 32; ++kt) {
    const int k0 = kt * 64;
#pragma unroll
    for (int i = 0; i < 4; ++i) {
      const int c = wid * 4 + i;
      const int row = c * 8 + srow;
      glds16(Ha + (size_t)row * 2048 + k0 + scol, &sA[c * 512]);
      glds16(Wd + (size_t)row * 2048 + k0 + scol, &sB[c * 512]);
    }
    __syncthreads();
#pragma unroll
    for (int ks = 0; ks < 2; ++ks) {
      const int ko = ks * 32 + (lane >> 4) * 8;
      s16x8 a[4], b[4];
#pragma unroll
      for (int mi = 0; mi < 4; ++mi)
        a[mi] = *(const s16x8*)&sA[(wm * 64 + mi * 16 + (lane & 15)) * 64 + ko];
#pragma unroll
      for (int ni = 0; ni < 4; ++ni)
        b[ni] = *(const s16x8*)&sB[(wn * 64 + ni * 16 + (lane & 15)) * 64 + ko];
#pragma unroll
      for (int mi = 0; mi < 4; ++mi)
#pragma unroll
        for (int ni = 0; ni < 4; ++ni)
          acc[mi][ni] = __builtin_amdgcn_mfma_f32_16x16x32_bf16(a[mi], b[ni], acc[mi][ni], 0, 0, 0);
    }
    __syncthreads();
  }
#pragma unroll
  for (int mi = 0; mi < 4; ++mi)
#pragma unroll
    for (int r = 0; r < 4; ++r) {
      const int lr = lr0 + wm * 64 + mi * 16 + (lane >> 4) * 4 + r;
      if (lr < cn) {
        const int tok = idx[e * 4096 + lr];
        const float wgt = cw[(size_t)tok * 4 + e];
        float* orow = out + (size_t)tok * 1024 + bn * 128 + wn * 64 + (lane & 15);
#pragma unroll
        for (int ni = 0; ni < 4; ++ni)
          atomicAdd(orow + ni * 16, acc[mi][ni][r] * wgt);
      }
    }
}

extern "C" void kernel_launch(void* const* d_in, const int* in_sizes, int n_in,
                              void* d_out, int out_size, void* d_ws, size_t ws_size,
                              hipStream_t stream) {
  const float* x     = (const float*)d_in[0];
  const float* wgate = (const float*)d_in[1];
  const float* wgp   = (const float*)d_in[2];
  const float* wup   = (const float*)d_in[3];
  const float* wdp   = (const float*)d_in[4];
  float* out = (float*)d_out;

  char* ws = (char*)d_ws;
  float* cw            = (float*)ws;                       // 64 KB
  int*   idx           = (int*)(ws + 65536);               // 64 KB
  int*   cnt           = (int*)(ws + 131072);              // 16 B
  int*   off           = (int*)(ws + 131136);              // 56 B
  unsigned short* Xb   = (unsigned short*)(ws + 131584);   // 8 MB
  unsigned short* Wcat = Xb   + (size_t)4096 * 1024;       // 32 MB
  unsigned short* Wdt  = Wcat + (size_t)4 * 4096 * 1024;   // 16 MB
  unsigned short* H    = Wdt  + (size_t)4 * 1024 * 2048;   // 9216 x 2048 bf16
  // total ~94 MiB (same layout as R9, which fit)

  hipMemsetAsync(cnt, 0, 16, stream);
  hipMemsetAsync(out, 0, (size_t)4096 * 1024 * 4, stream);
  k_routing<<<1024, 256, 0, stream>>>(x, wgate, cw, idx, cnt, Xb);
  k_offsets<<<1, 64, 0, stream>>>(cnt, off);
  k_tcvt_all<<<dim3(32, 16, 12), dim3(64, 4), 0, stream>>>(wgp, wup, wdp, Wcat, Wdt);

  k_gemm1<<<576, 512, 0, stream>>>(Xb, Wcat, H, idx, cnt, off);
  k_gemm2<<<544, 256, 0, stream>>>(H, Wdt, cw, idx, cnt, off, out);
}